// Round 1
// baseline (3604.014 us; speedup 1.0000x reference)
//
#include <hip/hip_runtime.h>
#include <cstdint>
#include <cstddef>

#define V_ 32000
#define E_ 512
#define H_ 1024
#define S_ 512
#define T_ 512
#define G4 4096  // 4*H

typedef unsigned long long u64;

__device__ __forceinline__ float sigm(float x) { return 1.0f / (1.0f + expf(-x)); }

// ---------------------------------------------------------------------------
// Xi[t, r] = emb[tok[t]] . Wih[r, :] + b1[r] + b2[r]
// tile 64t x 64r, BK=32, 256 threads, 4x4 micro-tile. K-major LDS (stride 68).
// ---------------------------------------------------------------------------
__global__ __launch_bounds__(256) void xi_gemm(
    const float* __restrict__ emb, const int* __restrict__ tok,
    const float* __restrict__ Wih, const float* __restrict__ b1,
    const float* __restrict__ b2, float* __restrict__ Xi) {
  __shared__ float As[32][68];
  __shared__ float Bs[32][68];
  __shared__ int ids[64];
  const int tid = threadIdx.x;
  const int tx = tid & 15, ty = tid >> 4;
  const int t0 = blockIdx.y * 64, r0 = blockIdx.x * 64;
  if (tid < 64) ids[tid] = tok[t0 + tid];
  __syncthreads();
  const int lrow = tid >> 2;        // 0..63
  const int lk   = (tid & 3) * 8;   // 0,8,16,24
  const long arow = (long)ids[lrow] * E_;
  const long brow = (long)(r0 + lrow) * E_;
  float acc[4][4] = {};
  for (int k0 = 0; k0 < E_; k0 += 32) {
    float4 a0 = *(const float4*)(emb + arow + k0 + lk);
    float4 a1 = *(const float4*)(emb + arow + k0 + lk + 4);
    float4 w0 = *(const float4*)(Wih + brow + k0 + lk);
    float4 w1 = *(const float4*)(Wih + brow + k0 + lk + 4);
    __syncthreads();  // previous compute done before overwriting LDS
    As[lk + 0][lrow] = a0.x; As[lk + 1][lrow] = a0.y; As[lk + 2][lrow] = a0.z; As[lk + 3][lrow] = a0.w;
    As[lk + 4][lrow] = a1.x; As[lk + 5][lrow] = a1.y; As[lk + 6][lrow] = a1.z; As[lk + 7][lrow] = a1.w;
    Bs[lk + 0][lrow] = w0.x; Bs[lk + 1][lrow] = w0.y; Bs[lk + 2][lrow] = w0.z; Bs[lk + 3][lrow] = w0.w;
    Bs[lk + 4][lrow] = w1.x; Bs[lk + 5][lrow] = w1.y; Bs[lk + 6][lrow] = w1.z; Bs[lk + 7][lrow] = w1.w;
    __syncthreads();
#pragma unroll
    for (int kk = 0; kk < 32; ++kk) {
      float4 av = *(const float4*)&As[kk][ty * 4];
      float4 bv = *(const float4*)&Bs[kk][tx * 4];
      float a_[4] = {av.x, av.y, av.z, av.w};
      float b_[4] = {bv.x, bv.y, bv.z, bv.w};
#pragma unroll
      for (int i = 0; i < 4; ++i)
#pragma unroll
        for (int j = 0; j < 4; ++j) acc[i][j] += a_[i] * b_[j];
    }
  }
#pragma unroll
  for (int i = 0; i < 4; ++i) {
    const int t = t0 + ty * 4 + i;
#pragma unroll
    for (int j = 0; j < 4; ++j) {
      const int r = r0 + tx * 4 + j;
      Xi[(size_t)t * G4 + r] = acc[i][j] + b1[r] + b2[r];
    }
  }
}

// ---------------------------------------------------------------------------
// Persistent recurrence: 256 WGs (1/CU) x 256 threads. WG w owns hidden units
// 4w..4w+3 -> 16 Whh rows held in VGPRs (fp32, 64 regs/thread). Sync between
// steps via (tag,value) 8B pairs, double-buffered. c-state never leaves regs.
// ---------------------------------------------------------------------------
__global__ __launch_bounds__(256) void lstm_seq(
    const float* __restrict__ Xi_enc, const float* __restrict__ Xi_dec,
    const float* __restrict__ Whh_enc, const float* __restrict__ Whh_dec,
    u64* __restrict__ hpair,   // [2][1024] (tag<<32)|f32bits, memset(0) before launch
    float* __restrict__ hs) {  // [512][1024] decoder hidden states
  __shared__ float h_lds[16 * 68];  // chunk-major, stride 68 (272B, 16B-aligned)
  __shared__ float gates_lds[16];
  const int tid = threadIdx.x;
  const int wg = blockIdx.x;
  const int r = tid >> 4;    // 0..15 (row within WG's 16 rows)
  const int c = tid & 15;    // 0..15 (64-elem chunk of h)
  const int gate = r >> 2, uu = r & 3;
  const int grow = gate * H_ + wg * 4 + uu;  // global Whh row
  const int c64 = c * 64;

  float4 w[16];
  {
    const float* wp = Whh_enc + (size_t)grow * H_ + c64;
#pragma unroll
    for (int q = 0; q < 16; ++q) w[q] = *(const float4*)(wp + q * 4);
  }
  const float* Xi = Xi_enc;
  float cstate = 0.f, h_own = 0.f;
  int dead = 0;

  for (int s = 0; s < 1024; ++s) {
    if (s == 512) {  // encoder -> decoder transition
      const float* wp = Whh_dec + (size_t)grow * H_ + c64;
#pragma unroll
      for (int q = 0; q < 16; ++q) w[q] = *(const float4*)(wp + q * 4);
      Xi = Xi_dec;
      if (tid < 4) cstate = tanhf(h_own);  // dc0 = tanh(enc_h); dh0 = enc_h (in hpair)
    }
    // prefetch this step's Xi contribution (independent of h)
    float xi = 0.f;
    if (c == 0) xi = Xi[(size_t)(s & 511) * G4 + grow];

    // poll the 4 h-pairs this thread stages (tag == s means input of step s)
    const u64* pp = hpair + (size_t)(s & 1) * H_ + tid * 4;
    const unsigned want = (unsigned)s;
    u64 p0, p1, p2, p3;
    {
      int tries = 0;
      for (;;) {
        p0 = __hip_atomic_load(pp + 0, __ATOMIC_RELAXED, __HIP_MEMORY_SCOPE_AGENT);
        p1 = __hip_atomic_load(pp + 1, __ATOMIC_RELAXED, __HIP_MEMORY_SCOPE_AGENT);
        p2 = __hip_atomic_load(pp + 2, __ATOMIC_RELAXED, __HIP_MEMORY_SCOPE_AGENT);
        p3 = __hip_atomic_load(pp + 3, __ATOMIC_RELAXED, __HIP_MEMORY_SCOPE_AGENT);
        if (dead || (((unsigned)(p0 >> 32) == want) && ((unsigned)(p1 >> 32) == want) &&
                     ((unsigned)(p2 >> 32) == want) && ((unsigned)(p3 >> 32) == want)))
          break;
        if (++tries > (1 << 22)) { dead = 1; break; }  // hang-safety: fail fast, not forever
        __builtin_amdgcn_s_sleep(1);
      }
    }
    {
      float* dst = &h_lds[(tid >> 4) * 68 + (tid & 15) * 4];
      dst[0] = __uint_as_float((unsigned)p0);
      dst[1] = __uint_as_float((unsigned)p1);
      dst[2] = __uint_as_float((unsigned)p2);
      dst[3] = __uint_as_float((unsigned)p3);
    }
    __syncthreads();  // sync #1: h staged

    float acc = 0.f;
    const float* hb = &h_lds[c * 68];
#pragma unroll
    for (int q = 0; q < 16; ++q) {
      float4 h4 = *(const float4*)(hb + q * 4);
      acc += w[q].x * h4.x + w[q].y * h4.y + w[q].z * h4.z + w[q].w * h4.w;
    }
    // reduce across the 16 chunk-lanes (contiguous lane groups within a wave)
    acc += __shfl_xor(acc, 8, 64);
    acc += __shfl_xor(acc, 4, 64);
    acc += __shfl_xor(acc, 2, 64);
    acc += __shfl_xor(acc, 1, 64);
    if (c == 0) gates_lds[r] = acc + xi;
    __syncthreads();  // sync #2: gates ready

    if (tid < 4) {  // unit owner: i,f,g,o at rows u, 4+u, 8+u, 12+u
      float ai = gates_lds[tid];
      float af = gates_lds[4 + tid];
      float ag = gates_lds[8 + tid];
      float ao = gates_lds[12 + tid];
      float i_ = sigm(ai), f_ = sigm(af), g_ = tanhf(ag), o_ = sigm(ao);
      cstate = f_ * cstate + i_ * g_;
      float h = o_ * tanhf(cstate);
      h_own = h;
      const int k = wg * 4 + tid;
      u64 pair = ((u64)(unsigned)(s + 1) << 32) | (u64)__float_as_uint(h);
      __hip_atomic_store(hpair + (size_t)((s + 1) & 1) * H_ + k, pair,
                         __ATOMIC_RELAXED, __HIP_MEMORY_SCOPE_AGENT);
      if (s >= 512) hs[(size_t)(s - 512) * H_ + k] = h;
    }
    // no 3rd barrier needed: next iter's LDS writes are fenced by sync #1/#2
  }
}

// ---------------------------------------------------------------------------
// logits tile GEMM (128t x 128v, BK=32, 8x8 micro) with fused partial
// logsumexp epilogue. Never materializes the [512 x 32000] logits.
// ---------------------------------------------------------------------------
#define PHYS(j) ((j) + (((j) >> 5) << 2))  // +4-word shift per 32-col block (bank spread)

__global__ __launch_bounds__(256) void logits_lse(
    const float* __restrict__ hs, const float* __restrict__ Wout,
    const float* __restrict__ bout, const int* __restrict__ tgt,
    float* __restrict__ pmax, float* __restrict__ psum,
    float* __restrict__ tgtlog) {
  __shared__ float As[32][140];
  __shared__ float Bs[32][140];
  __shared__ float red[128][17];
  __shared__ float Mlds[128];
  __shared__ int tg[128];
  const int tid = threadIdx.x;
  const int tx = tid & 15, ty = tid >> 4;
  const int t0 = blockIdx.y * 128, v0 = blockIdx.x * 128;
  if (tid < 128) tg[tid] = tgt[t0 + tid];
  const int lrow = tid >> 1;        // 0..127
  const int lk   = (tid & 1) * 16;  // 0 or 16
  const float* ap = hs + (size_t)(t0 + lrow) * H_ + lk;
  const float* bp = Wout + (size_t)(v0 + lrow) * H_ + lk;
  const int pl = PHYS(lrow);
  const int aoff = PHYS(ty * 8);
  const int boff = PHYS(tx * 8);
  float acc[8][8] = {};
  for (int k0 = 0; k0 < H_; k0 += 32) {
    float4 a[4], b[4];
#pragma unroll
    for (int q = 0; q < 4; ++q) {
      a[q] = *(const float4*)(ap + k0 + q * 4);
      b[q] = *(const float4*)(bp + k0 + q * 4);
    }
    __syncthreads();
#pragma unroll
    for (int q = 0; q < 4; ++q) {
      As[lk + q * 4 + 0][pl] = a[q].x; As[lk + q * 4 + 1][pl] = a[q].y;
      As[lk + q * 4 + 2][pl] = a[q].z; As[lk + q * 4 + 3][pl] = a[q].w;
      Bs[lk + q * 4 + 0][pl] = b[q].x; Bs[lk + q * 4 + 1][pl] = b[q].y;
      Bs[lk + q * 4 + 2][pl] = b[q].z; Bs[lk + q * 4 + 3][pl] = b[q].w;
    }
    __syncthreads();
#pragma unroll
    for (int kk = 0; kk < 32; ++kk) {
      float av[8], bv[8];
      *(float4*)&av[0] = *(const float4*)&As[kk][aoff];
      *(float4*)&av[4] = *(const float4*)&As[kk][aoff + 4];
      *(float4*)&bv[0] = *(const float4*)&Bs[kk][boff];
      *(float4*)&bv[4] = *(const float4*)&Bs[kk][boff + 4];
#pragma unroll
      for (int i = 0; i < 8; ++i)
#pragma unroll
        for (int j = 0; j < 8; ++j) acc[i][j] += av[i] * bv[j];
    }
  }
  // ---- fused epilogue: bias, row max, row sumexp, target logit ----
  float bv8[8];
#pragma unroll
  for (int j = 0; j < 8; ++j) bv8[j] = bout[v0 + tx * 8 + j];
#pragma unroll
  for (int i = 0; i < 8; ++i) {
    float m = -3.0e38f;
#pragma unroll
    for (int j = 0; j < 8; ++j) {
      acc[i][j] += bv8[j];
      m = fmaxf(m, acc[i][j]);
    }
    red[ty * 8 + i][tx] = m;
  }
  __syncthreads();
  if (tid < 128) {
    float M = -3.0e38f;
#pragma unroll
    for (int x = 0; x < 16; ++x) M = fmaxf(M, red[tid][x]);
    Mlds[tid] = M;
  }
  __syncthreads();
#pragma unroll
  for (int i = 0; i < 8; ++i) {
    float M = Mlds[ty * 8 + i];
    float ssum = 0.f;
#pragma unroll
    for (int j = 0; j < 8; ++j) ssum += expf(acc[i][j] - M);
    red[ty * 8 + i][tx] = ssum;
  }
  __syncthreads();
  if (tid < 128) {
    float S = 0.f;
#pragma unroll
    for (int x = 0; x < 16; ++x) S += red[tid][x];
    pmax[(size_t)(t0 + tid) * 250 + blockIdx.x] = Mlds[tid];
    psum[(size_t)(t0 + tid) * 250 + blockIdx.x] = S;
  }
#pragma unroll
  for (int i = 0; i < 8; ++i) {
    const int t = t0 + ty * 8 + i;
    const int loc = tg[ty * 8 + i] - v0 - tx * 8;
    if (loc >= 0 && loc < 8) {
#pragma unroll
      for (int j = 0; j < 8; ++j)
        if (j == loc) tgtlog[t] = acc[i][j];  // static indexing: no scratch spill
    }
  }
}

// ---------------------------------------------------------------------------
// combine 250 (max, sumexp) partials per row -> loss[t] = lse - logit[target]
// ---------------------------------------------------------------------------
__global__ __launch_bounds__(256) void reduce_loss(
    const float* __restrict__ pmax, const float* __restrict__ psum,
    const float* __restrict__ tgtlog, float* __restrict__ out) {
  __shared__ float sm[256];
  __shared__ float ss[256];
  const int t = blockIdx.x, tid = threadIdx.x;
  float m = -3.0e38f;
  if (tid < 250) m = pmax[(size_t)t * 250 + tid];
  sm[tid] = m;
  __syncthreads();
  for (int s = 128; s > 0; s >>= 1) {
    if (tid < s) sm[tid] = fmaxf(sm[tid], sm[tid + s]);
    __syncthreads();
  }
  const float M = sm[0];
  float sv = 0.f;
  if (tid < 250) sv = psum[(size_t)t * 250 + tid] * expf(m - M);
  ss[tid] = sv;
  __syncthreads();
  for (int s = 128; s > 0; s >>= 1) {
    if (tid < s) ss[tid] += ss[tid + s];
    __syncthreads();
  }
  if (tid == 0) out[t] = M + logf(ss[0]) - tgtlog[t];
}

// ---------------------------------------------------------------------------
extern "C" void kernel_launch(void* const* d_in, const int* in_sizes, int n_in,
                              void* d_out, int out_size, void* d_ws, size_t ws_size,
                              hipStream_t stream) {
  const int*   source    = (const int*)  d_in[0];
  const int*   target    = (const int*)  d_in[1];
  const float* enc_embed = (const float*)d_in[2];
  const float* enc_Wih   = (const float*)d_in[3];
  const float* enc_Whh   = (const float*)d_in[4];
  const float* enc_bih   = (const float*)d_in[5];
  const float* enc_bhh   = (const float*)d_in[6];
  const float* dec_embed = (const float*)d_in[7];
  const float* dec_Wih   = (const float*)d_in[8];
  const float* dec_Whh   = (const float*)d_in[9];
  const float* dec_bih   = (const float*)d_in[10];
  const float* dec_bhh   = (const float*)d_in[11];
  const float* Wout      = (const float*)d_in[12];
  const float* bout      = (const float*)d_in[13];
  float* out = (float*)d_out;

  char* ws = (char*)d_ws;
  float* Xi_enc = (float*)(ws);                    // 512*4096*4 = 8 MB
  float* Xi_dec = (float*)(ws + 8388608);          // 8 MB
  float* hs     = (float*)(ws + 16777216);         // 2 MB
  u64*   hpair  = (u64*)  (ws + 18874368);         // 16 KB
  float* pmax   = (float*)(ws + 18890752);         // 512*250*4 = 500 KB
  float* psum   = (float*)(ws + 19402752);         // 500 KB
  float* tgtlog = (float*)(ws + 19914752);         // 2 KB

  hipMemsetAsync((void*)hpair, 0, 2 * H_ * sizeof(u64), stream);  // h0=0, tag=0
  xi_gemm<<<dim3(64, 8), 256, 0, stream>>>(enc_embed, source, enc_Wih, enc_bih, enc_bhh, Xi_enc);
  xi_gemm<<<dim3(64, 8), 256, 0, stream>>>(dec_embed, target, dec_Wih, dec_bih, dec_bhh, Xi_dec);
  lstm_seq<<<256, 256, 0, stream>>>(Xi_enc, Xi_dec, enc_Whh, dec_Whh, hpair, hs);
  logits_lse<<<dim3(250, 4), 256, 0, stream>>>(hs, Wout, bout, target, pmax, psum, tgtlog);
  reduce_loss<<<512, 256, 0, stream>>>(pmax, psum, tgtlog, out);
}

// Round 2
// 3043.361 us; speedup vs baseline: 1.1842x; 1.1842x over previous
//
#include <hip/hip_runtime.h>
#include <cstdint>
#include <cstddef>

#define V_ 32000
#define E_ 512
#define H_ 1024
#define S_ 512
#define T_ 512
#define G4 4096  // 4*H

typedef unsigned long long u64;

__device__ __forceinline__ float sigm(float x) { return 1.0f / (1.0f + expf(-x)); }

// ---------------------------------------------------------------------------
// Xi[t, r] = emb[tok[t]] . Wih[r, :] + b1[r] + b2[r]
// tile 64t x 64r, BK=32, 256 threads, 4x4 micro-tile. K-major LDS (stride 68).
// ---------------------------------------------------------------------------
__global__ __launch_bounds__(256) void xi_gemm(
    const float* __restrict__ emb, const int* __restrict__ tok,
    const float* __restrict__ Wih, const float* __restrict__ b1,
    const float* __restrict__ b2, float* __restrict__ Xi) {
  __shared__ float As[32][68];
  __shared__ float Bs[32][68];
  __shared__ int ids[64];
  const int tid = threadIdx.x;
  const int tx = tid & 15, ty = tid >> 4;
  const int t0 = blockIdx.y * 64, r0 = blockIdx.x * 64;
  if (tid < 64) ids[tid] = tok[t0 + tid];
  __syncthreads();
  const int lrow = tid >> 2;        // 0..63
  const int lk   = (tid & 3) * 8;   // 0,8,16,24
  const long arow = (long)ids[lrow] * E_;
  const long brow = (long)(r0 + lrow) * E_;
  float acc[4][4] = {};
  for (int k0 = 0; k0 < E_; k0 += 32) {
    float4 a0 = *(const float4*)(emb + arow + k0 + lk);
    float4 a1 = *(const float4*)(emb + arow + k0 + lk + 4);
    float4 w0 = *(const float4*)(Wih + brow + k0 + lk);
    float4 w1 = *(const float4*)(Wih + brow + k0 + lk + 4);
    __syncthreads();  // previous compute done before overwriting LDS
    As[lk + 0][lrow] = a0.x; As[lk + 1][lrow] = a0.y; As[lk + 2][lrow] = a0.z; As[lk + 3][lrow] = a0.w;
    As[lk + 4][lrow] = a1.x; As[lk + 5][lrow] = a1.y; As[lk + 6][lrow] = a1.z; As[lk + 7][lrow] = a1.w;
    Bs[lk + 0][lrow] = w0.x; Bs[lk + 1][lrow] = w0.y; Bs[lk + 2][lrow] = w0.z; Bs[lk + 3][lrow] = w0.w;
    Bs[lk + 4][lrow] = w1.x; Bs[lk + 5][lrow] = w1.y; Bs[lk + 6][lrow] = w1.z; Bs[lk + 7][lrow] = w1.w;
    __syncthreads();
#pragma unroll
    for (int kk = 0; kk < 32; ++kk) {
      float4 av = *(const float4*)&As[kk][ty * 4];
      float4 bv = *(const float4*)&Bs[kk][tx * 4];
      float a_[4] = {av.x, av.y, av.z, av.w};
      float b_[4] = {bv.x, bv.y, bv.z, bv.w};
#pragma unroll
      for (int i = 0; i < 4; ++i)
#pragma unroll
        for (int j = 0; j < 4; ++j) acc[i][j] += a_[i] * b_[j];
    }
  }
#pragma unroll
  for (int i = 0; i < 4; ++i) {
    const int t = t0 + ty * 4 + i;
#pragma unroll
    for (int j = 0; j < 4; ++j) {
      const int r = r0 + tx * 4 + j;
      Xi[(size_t)t * G4 + r] = acc[i][j] + b1[r] + b2[r];
    }
  }
}

// ---------------------------------------------------------------------------
// Persistent recurrence v2: 64 WGs x 1024 threads. WG w owns 16 hidden units
// -> 64 Whh rows, 64 weight floats/thread in VGPRs. Sync: tagged 8B pairs,
// but only wave 0 (64 lanes) polls one REPRESENTATIVE pair per producer WG
// (4096 atomic loads/round device-wide vs 262144 in v1); all 1024 threads
// then bulk-read their pair once (optimistically preloaded), micro-spin on
// the tag to absorb line-level visibility skew. Xi fetch is now exactly one
// 64B line per 16 rows (no overfetch). Double-buffer overrun safety: a pair
// tagged s+1 can only be published after every WG consumed tag s-1 (global
// dependence), proof as v1.
// ---------------------------------------------------------------------------
__global__ __launch_bounds__(1024, 4) void lstm_seq(
    const float* __restrict__ Xi_enc, const float* __restrict__ Xi_dec,
    const float* __restrict__ Whh_enc, const float* __restrict__ Whh_dec,
    u64* __restrict__ hpair,   // [2][1024] (tag<<32)|f32bits, memset(0) before launch
    float* __restrict__ hs) {  // [512][1024] decoder hidden states
  __shared__ float h_lds[16 * 68 + 4];  // chunk-major, stride 68 (2-way bank alias = free)
  __shared__ float gates_lds[64];
  const int tid = threadIdx.x;
  const int wg = blockIdx.x;          // 0..63
  const int r = tid >> 4;             // 0..63 local row
  const int c = tid & 15;             // 0..15 -> h chunk [c*64, c*64+64)
  const int gate = r >> 4, uu = r & 15;
  const int grow = gate * H_ + wg * 16 + uu;  // global Whh row
  const int c64 = c * 64;

  float4 w[16];
  {
    const float* wp = Whh_enc + (size_t)grow * H_ + c64;
#pragma unroll
    for (int q = 0; q < 16; ++q) w[q] = *(const float4*)(wp + q * 4);
  }
  const float* Xi = Xi_enc;
  float cstate = 0.f, h_own = 0.f;
  int dead = 0;

  for (int s = 0; s < 1024; ++s) {
    if (s == 512) {  // encoder -> decoder transition
      const float* wp = Whh_dec + (size_t)grow * H_ + c64;
#pragma unroll
      for (int q = 0; q < 16; ++q) w[q] = *(const float4*)(wp + q * 4);
      Xi = Xi_dec;
      if (tid < 16) cstate = tanhf(h_own);  // dc0 = tanh(enc_h); dh0 = enc_h (in pairs)
    }
    // prefetch this step's Xi contribution (independent of h); one 64B line
    // per 16-row gate cluster -> 4 lines/WG/step, zero overfetch
    float xi = 0.f;
    if (c == 0) xi = Xi[(size_t)(s & 511) * G4 + grow];

    const u64* pbase = hpair + (size_t)(s & 1) * H_;
    const unsigned want = (unsigned)s;

    // optimistic preload of this thread's pair (may be stale; checked below)
    u64 p = __hip_atomic_load(pbase + tid, __ATOMIC_RELAXED, __HIP_MEMORY_SCOPE_AGENT);

    // wave 0: poll 64 representative pairs (unit 0 of each producer WG)
    if (tid < 64) {
      const u64* fp = pbase + tid * 16;
      int tries = 0;
      for (;;) {
        u64 f = __hip_atomic_load(fp, __ATOMIC_RELAXED, __HIP_MEMORY_SCOPE_AGENT);
        bool ok = ((int)((unsigned)(f >> 32) - want)) >= 0;
        if (__ballot(ok) == ~0ull) break;      // uniform: all lanes exit together
        if (++tries > (1 << 20)) break;        // hang safety
        __builtin_amdgcn_s_sleep(1);
      }
    }
    __syncthreads();  // barrier A: all producers have published step-s pairs

    // validate optimistic preload; rare micro-spin absorbs visibility skew
    if ((unsigned)(p >> 32) != want) {
      int tries = 0;
      do {
        p = __hip_atomic_load(pbase + tid, __ATOMIC_RELAXED, __HIP_MEMORY_SCOPE_AGENT);
        if (++tries > (1 << 20)) { dead = 1; break; }
      } while ((unsigned)(p >> 32) != want && !dead);
    }
    h_lds[(tid >> 6) * 68 + (tid & 63)] = __uint_as_float((unsigned)p);
    __syncthreads();  // barrier B: h staged in LDS

    float acc = 0.f;
    const float* hb = &h_lds[c * 68];
#pragma unroll
    for (int q = 0; q < 16; ++q) {
      float4 h4 = *(const float4*)(hb + q * 4);
      acc += w[q].x * h4.x + w[q].y * h4.y + w[q].z * h4.z + w[q].w * h4.w;
    }
    // reduce across the 16 chunk-lanes (consecutive lanes within a wave)
    acc += __shfl_xor(acc, 8, 64);
    acc += __shfl_xor(acc, 4, 64);
    acc += __shfl_xor(acc, 2, 64);
    acc += __shfl_xor(acc, 1, 64);
    if (c == 0) gates_lds[r] = acc + xi;
    __syncthreads();  // barrier C: gates ready

    if (tid < 16) {  // unit owner u: rows u, 16+u, 32+u, 48+u = i,f,g,o
      float ai = gates_lds[tid];
      float af = gates_lds[16 + tid];
      float ag = gates_lds[32 + tid];
      float ao = gates_lds[48 + tid];
      float i_ = sigm(ai), f_ = sigm(af), g_ = tanhf(ag), o_ = sigm(ao);
      cstate = f_ * cstate + i_ * g_;
      float h = o_ * tanhf(cstate);
      h_own = h;
      const int k = wg * 16 + tid;
      u64 pair = ((u64)(unsigned)(s + 1) << 32) | (u64)__float_as_uint(h);
      __hip_atomic_store(hpair + (size_t)((s + 1) & 1) * H_ + k, pair,
                         __ATOMIC_RELAXED, __HIP_MEMORY_SCOPE_AGENT);
      if (s >= 512) hs[(size_t)(s - 512) * H_ + k] = h;
    }
    // no 4th barrier: next iter's h_lds writes are fenced by barriers A/B
  }
}

// ---------------------------------------------------------------------------
// logits tile GEMM (128t x 128v, BK=32, 8x8 micro) with fused partial
// logsumexp epilogue. Never materializes the [512 x 32000] logits.
// ---------------------------------------------------------------------------
#define PHYS(j) ((j) + (((j) >> 5) << 2))  // +4-word shift per 32-col block (bank spread)

__global__ __launch_bounds__(256) void logits_lse(
    const float* __restrict__ hs, const float* __restrict__ Wout,
    const float* __restrict__ bout, const int* __restrict__ tgt,
    float* __restrict__ pmax, float* __restrict__ psum,
    float* __restrict__ tgtlog) {
  __shared__ float As[32][140];
  __shared__ float Bs[32][140];
  __shared__ float red[128][17];
  __shared__ float Mlds[128];
  __shared__ int tg[128];
  const int tid = threadIdx.x;
  const int tx = tid & 15, ty = tid >> 4;
  const int t0 = blockIdx.y * 128, v0 = blockIdx.x * 128;
  if (tid < 128) tg[tid] = tgt[t0 + tid];
  const int lrow = tid >> 1;        // 0..127
  const int lk   = (tid & 1) * 16;  // 0 or 16
  const float* ap = hs + (size_t)(t0 + lrow) * H_ + lk;
  const float* bp = Wout + (size_t)(v0 + lrow) * H_ + lk;
  const int pl = PHYS(lrow);
  const int aoff = PHYS(ty * 8);
  const int boff = PHYS(tx * 8);
  float acc[8][8] = {};
  for (int k0 = 0; k0 < H_; k0 += 32) {
    float4 a[4], b[4];
#pragma unroll
    for (int q = 0; q < 4; ++q) {
      a[q] = *(const float4*)(ap + k0 + q * 4);
      b[q] = *(const float4*)(bp + k0 + q * 4);
    }
    __syncthreads();
#pragma unroll
    for (int q = 0; q < 4; ++q) {
      As[lk + q * 4 + 0][pl] = a[q].x; As[lk + q * 4 + 1][pl] = a[q].y;
      As[lk + q * 4 + 2][pl] = a[q].z; As[lk + q * 4 + 3][pl] = a[q].w;
      Bs[lk + q * 4 + 0][pl] = b[q].x; Bs[lk + q * 4 + 1][pl] = b[q].y;
      Bs[lk + q * 4 + 2][pl] = b[q].z; Bs[lk + q * 4 + 3][pl] = b[q].w;
    }
    __syncthreads();
#pragma unroll
    for (int kk = 0; kk < 32; ++kk) {
      float av[8], bv[8];
      *(float4*)&av[0] = *(const float4*)&As[kk][aoff];
      *(float4*)&av[4] = *(const float4*)&As[kk][aoff + 4];
      *(float4*)&bv[0] = *(const float4*)&Bs[kk][boff];
      *(float4*)&bv[4] = *(const float4*)&Bs[kk][boff + 4];
#pragma unroll
      for (int i = 0; i < 8; ++i)
#pragma unroll
        for (int j = 0; j < 8; ++j) acc[i][j] += av[i] * bv[j];
    }
  }
  // ---- fused epilogue: bias, row max, row sumexp, target logit ----
  float bv8[8];
#pragma unroll
  for (int j = 0; j < 8; ++j) bv8[j] = bout[v0 + tx * 8 + j];
#pragma unroll
  for (int i = 0; i < 8; ++i) {
    float m = -3.0e38f;
#pragma unroll
    for (int j = 0; j < 8; ++j) {
      acc[i][j] += bv8[j];
      m = fmaxf(m, acc[i][j]);
    }
    red[ty * 8 + i][tx] = m;
  }
  __syncthreads();
  if (tid < 128) {
    float M = -3.0e38f;
#pragma unroll
    for (int x = 0; x < 16; ++x) M = fmaxf(M, red[tid][x]);
    Mlds[tid] = M;
  }
  __syncthreads();
#pragma unroll
  for (int i = 0; i < 8; ++i) {
    float M = Mlds[ty * 8 + i];
    float ssum = 0.f;
#pragma unroll
    for (int j = 0; j < 8; ++j) ssum += expf(acc[i][j] - M);
    red[ty * 8 + i][tx] = ssum;
  }
  __syncthreads();
  if (tid < 128) {
    float S = 0.f;
#pragma unroll
    for (int x = 0; x < 16; ++x) S += red[tid][x];
    pmax[(size_t)(t0 + tid) * 250 + blockIdx.x] = Mlds[tid];
    psum[(size_t)(t0 + tid) * 250 + blockIdx.x] = S;
  }
#pragma unroll
  for (int i = 0; i < 8; ++i) {
    const int t = t0 + ty * 8 + i;
    const int loc = tg[ty * 8 + i] - v0 - tx * 8;
    if (loc >= 0 && loc < 8) {
#pragma unroll
      for (int j = 0; j < 8; ++j)
        if (j == loc) tgtlog[t] = acc[i][j];  // static indexing: no scratch spill
    }
  }
}

// ---------------------------------------------------------------------------
// combine 250 (max, sumexp) partials per row -> loss[t] = lse - logit[target]
// ---------------------------------------------------------------------------
__global__ __launch_bounds__(256) void reduce_loss(
    const float* __restrict__ pmax, const float* __restrict__ psum,
    const float* __restrict__ tgtlog, float* __restrict__ out) {
  __shared__ float sm[256];
  __shared__ float ss[256];
  const int t = blockIdx.x, tid = threadIdx.x;
  float m = -3.0e38f;
  if (tid < 250) m = pmax[(size_t)t * 250 + tid];
  sm[tid] = m;
  __syncthreads();
  for (int s = 128; s > 0; s >>= 1) {
    if (tid < s) sm[tid] = fmaxf(sm[tid], sm[tid + s]);
    __syncthreads();
  }
  const float M = sm[0];
  float sv = 0.f;
  if (tid < 250) sv = psum[(size_t)t * 250 + tid] * expf(m - M);
  ss[tid] = sv;
  __syncthreads();
  for (int s = 128; s > 0; s >>= 1) {
    if (tid < s) ss[tid] += ss[tid + s];
    __syncthreads();
  }
  if (tid == 0) out[t] = M + logf(ss[0]) - tgtlog[t];
}

// ---------------------------------------------------------------------------
extern "C" void kernel_launch(void* const* d_in, const int* in_sizes, int n_in,
                              void* d_out, int out_size, void* d_ws, size_t ws_size,
                              hipStream_t stream) {
  const int*   source    = (const int*)  d_in[0];
  const int*   target    = (const int*)  d_in[1];
  const float* enc_embed = (const float*)d_in[2];
  const float* enc_Wih   = (const float*)d_in[3];
  const float* enc_Whh   = (const float*)d_in[4];
  const float* enc_bih   = (const float*)d_in[5];
  const float* enc_bhh   = (const float*)d_in[6];
  const float* dec_embed = (const float*)d_in[7];
  const float* dec_Wih   = (const float*)d_in[8];
  const float* dec_Whh   = (const float*)d_in[9];
  const float* dec_bih   = (const float*)d_in[10];
  const float* dec_bhh   = (const float*)d_in[11];
  const float* Wout      = (const float*)d_in[12];
  const float* bout      = (const float*)d_in[13];
  float* out = (float*)d_out;

  char* ws = (char*)d_ws;
  float* Xi_enc = (float*)(ws);                    // 512*4096*4 = 8 MB
  float* Xi_dec = (float*)(ws + 8388608);          // 8 MB
  float* hs     = (float*)(ws + 16777216);         // 2 MB
  u64*   hpair  = (u64*)  (ws + 18874368);         // 16 KB
  float* pmax   = (float*)(ws + 18890752);         // 512*250*4 = 500 KB
  float* psum   = (float*)(ws + 19402752);         // 500 KB
  float* tgtlog = (float*)(ws + 19914752);         // 2 KB

  hipMemsetAsync((void*)hpair, 0, 2 * H_ * sizeof(u64), stream);  // h0=0, tag=0
  xi_gemm<<<dim3(64, 8), 256, 0, stream>>>(enc_embed, source, enc_Wih, enc_bih, enc_bhh, Xi_enc);
  xi_gemm<<<dim3(64, 8), 256, 0, stream>>>(dec_embed, target, dec_Wih, dec_bih, dec_bhh, Xi_dec);
  lstm_seq<<<64, 1024, 0, stream>>>(Xi_enc, Xi_dec, enc_Whh, dec_Whh, hpair, hs);
  logits_lse<<<dim3(250, 4), 256, 0, stream>>>(hs, Wout, bout, target, pmax, psum, tgtlog);
  reduce_loss<<<512, 256, 0, stream>>>(pmax, psum, tgtlog, out);
}